// Round 13
// baseline (61.065 us; speedup 1.0000x reference)
//
#include <hip/hip_runtime.h>

#define NB 8192
#define ND 128
#define MARGINF 0.3f
#define FLTMAX 3.402823466e+38f
#define A_TILES 8             // scan cap: 8 x 16 = 128 cols
#define FIN_BLOCKS 1024       // 8 row-groups x 128 chunks
#define DIAG_COL 0xFFFFFFFEULL

// ws layout (bytes):
//   [0]      uint  pd            (reset by scan block 0 each call)
//   [64]     float dapw[8192]    dense
//   [32832]  float row_loss[8192] dense (-1.0f = unresolved sentinel)
//   [65600]  int   list[8192]    dense (row | -1)
//   [98368]  u64   idxval[8192]  dense (key or ~0; finish atomicMins)

__device__ __forceinline__ float dot4(float4 x, float4 y) {
    return x.x * y.x + x.y * y.y + x.z * y.z + x.w * y.w;
}

// Butterfly sum within each 32-lane half.
__device__ __forceinline__ float half_reduce(float v) {
    v += __shfl_xor(v, 1, 64);
    v += __shfl_xor(v, 2, 64);
    v += __shfl_xor(v, 4, 64);
    v += __shfl_xor(v, 8, 64);
    v += __shfl_xor(v, 16, 64);
    return v;
}

// Lane owning local column c: col(L) = 2*(L&31) + (L>>5).
__device__ __forceinline__ int owner(int c) {
    return (c & 1) ? 32 + (c >> 1) : (c >> 1);
}

__device__ __forceinline__ int first_col_from_mask(unsigned long long mask) {
    const unsigned int lo = (unsigned int)mask;          // even local cols
    const unsigned int hi = (unsigned int)(mask >> 32);  // odd local cols
    const int ce = lo ? 2 * (__ffs(lo) - 1)     : 0x7fffffff;
    const int co = hi ? 2 * (__ffs(hi) - 1) + 1 : 0x7fffffff;
    return ce < co ? ce : co;
}

// Node 1: one row per wave, scan cols [0,128) in 16-col mini-tiles, early exit.
// Dense outputs -> no init node. Block 0 resets the pd counter for node 2.
__global__ __launch_bounds__(256) void triplet_scan(const float* __restrict__ a,
                                                    const float* __restrict__ p,
                                                    const float* __restrict__ n,
                                                    unsigned int* __restrict__ pd,
                                                    float* __restrict__ dapw,
                                                    float* __restrict__ row_loss,
                                                    int* __restrict__ list,
                                                    unsigned long long* __restrict__ idxval) {
    const int tid  = threadIdx.x;
    const int wave = tid >> 6;
    const int lane = tid & 63;
    const int q    = lane & 31;
    const int h    = lane >> 5;
    const int row  = blockIdx.x * 4 + wave;

    if (blockIdx.x == 0 && tid == 0) *pd = 0u;   // boundary orders this for node 2

    const float4 a4 = *(const float4*)(a + (size_t)row * ND + q * 4);
    const float4 p4 = *(const float4*)(p + (size_t)row * ND + q * 4);
    const float dist_ap = half_reduce(dot4(a4, p4));
    const float thresh  = dist_ap + MARGINF;

    float loss = -1.0f;                       // unresolved sentinel
    bool resolved = false;
    for (int t = 0; t < A_TILES && !resolved; ++t) {
        float myval = FLTMAX;
        #pragma unroll
        for (int k = 0; k < 8; ++k) {
            const int col = t * 16 + 2 * k + h;
            const float4 nv = *(const float4*)(n + (size_t)col * ND + q * 4);
            const float v = half_reduce(dot4(a4, nv));
            if (q == k) myval = v;
        }
        const unsigned long long mask = __ballot(myval < thresh);
        if (mask) {  // wave-uniform: first tile with a hit; min col inside is exact
            const int c = first_col_from_mask(mask);
            const float dist_an = __shfl(myval, owner(c), 64);
            const float l = dist_an - dist_ap + MARGINF;
            loss = l > 0.f ? l : 0.f;
            resolved = true;
        }
    }
    if (lane == 0) {
        dapw[row]     = dist_ap;
        row_loss[row] = loss;
        list[row]     = resolved ? -1 : row;
        if (!resolved) idxval[row] = ~0ULL;
    }
}

// Node 2: block (rg, cg); compact rg-slice's unresolved rows in LDS, each wave
// does one (row, chunk cg) tile -> relaxed atomicMin. Then done-counter; the
// last block runs the finale in-kernel (fixed-order deterministic sum).
__global__ __launch_bounds__(256) void triplet_finish(const float* __restrict__ a,
                                                      const float* __restrict__ n,
                                                      const float* __restrict__ dapw,
                                                      const float* __restrict__ row_loss,
                                                      const int* __restrict__ list,
                                                      unsigned long long* __restrict__ idxval,
                                                      unsigned int* __restrict__ pd,
                                                      float* __restrict__ out) {
    __shared__ int s_rows[1024];
    __shared__ int s_cnt;
    __shared__ int s_last;
    __shared__ double s_red[256];
    const int tid  = threadIdx.x;
    const int wave = tid >> 6;
    const int lane = tid & 63;
    const int q    = lane & 31;
    const int h    = lane >> 5;
    const int cg   = blockIdx.x & 127;        // chunk index [0,128)
    const int rg   = blockIdx.x >> 7;         // row-group [0,8)
    const int tb   = cg << 6;                 // chunk base column

    if (tid == 0) s_cnt = 0;
    __syncthreads();
    #pragma unroll
    for (int i = 0; i < 4; ++i) {             // 1024 ints, coalesced
        const int v = list[rg * 1024 + i * 256 + tid];
        if (v >= 0) s_rows[atomicAdd(&s_cnt, 1)] = v;   // LDS atomic; order moot
    }
    __syncthreads();
    const int cnt = s_cnt;

    for (int t = wave; t < cnt; t += 4) {
        const int r  = s_rows[t];
        const float th = dapw[r] + MARGINF;
        const float4 a4 = *(const float4*)(a + (size_t)r * ND + q * 4);

        float myval = FLTMAX;
        #pragma unroll
        for (int k = 0; k < 32; ++k) {
            const int col = tb + 2 * k + h;
            const float4 nv = *(const float4*)(n + (size_t)col * ND + q * 4);
            const float v = half_reduce(dot4(a4, nv));   // bit-identical to scan
            if (q == k) myval = v;
        }
        if ((r >> 6) == cg) {                 // diag candidate (loses to any hit)
            const float dv = __shfl(myval, owner(r - tb), 64);
            if (lane == 0) {
                const unsigned long long dkey =
                    (DIAG_COL << 32) | (unsigned long long)__float_as_uint(dv);
                atomicMin(&idxval[r], dkey);
            }
        }
        const unsigned long long mask = __ballot(myval < th);
        if (mask) {                           // wave-uniform
            const int c = first_col_from_mask(mask);
            const float fv = __shfl(myval, owner(c), 64);
            if (lane == 0) {
                const unsigned long long key =
                    ((unsigned long long)(tb + c) << 32)
                    | (unsigned long long)__float_as_uint(fv);
                atomicMin(&idxval[r], key);   // min col wins; order-independent
            }
        }
    }

    // Arrival: barrier drains this block's atomics (vmcnt(0) before s_barrier),
    // so our Mins are globally performed before we increment pd.
    __syncthreads();
    if (tid == 0) {
        const unsigned int old = atomicAdd(pd, 1u);
        s_last = (old == FIN_BLOCKS - 1u) ? 1 : 0;
    }
    __syncthreads();
    if (!s_last) return;

    // Finale (last block only): fixed-order deterministic sum.
    double sum = 0.0;
    #pragma unroll
    for (int i = 0; i < NB / 256; ++i) {      // 32 iters, fixed order
        const int w = i * 256 + tid;
        float v = row_loss[w];
        if (v < 0.f) {                        // sentinel: read atomics' result
            const unsigned long long u = atomicAdd(&idxval[w], 0ULL);
            const float an_v = __uint_as_float((unsigned int)u);
            const float l = an_v - dapw[w] + MARGINF;
            v = l > 0.f ? l : 0.f;
        }
        sum += (double)v;
    }
    s_red[tid] = sum;
    __syncthreads();
    #pragma unroll
    for (int off = 128; off; off >>= 1) {
        if (tid < off) s_red[tid] += s_red[tid + off];
        __syncthreads();
    }
    if (tid == 0) out[0] = (float)(s_red[0] / (double)NB);
}

extern "C" void kernel_launch(void* const* d_in, const int* in_sizes, int n_in,
                              void* d_out, int out_size, void* d_ws, size_t ws_size,
                              hipStream_t stream) {
    const float* a = (const float*)d_in[0];
    const float* p = (const float*)d_in[1];
    const float* n = (const float*)d_in[2];
    float* out = (float*)d_out;
    char*  ws  = (char*)d_ws;
    unsigned int*       pd       = (unsigned int*)ws;
    float*              dapw     = (float*)(ws + 64);
    float*              row_loss = (float*)(ws + 32832);
    int*                list     = (int*)(ws + 65600);
    unsigned long long* idxval   = (unsigned long long*)(ws + 98368);

    triplet_scan  <<<NB / 4, 256, 0, stream>>>(a, p, n, pd, dapw, row_loss, list, idxval);
    triplet_finish<<<FIN_BLOCKS, 256, 0, stream>>>(a, n, dapw, row_loss, list, idxval, pd, out);
}

// Round 14
// 60.498 us; speedup vs baseline: 1.0094x; 1.0094x over previous
//
#include <hip/hip_runtime.h>

#define NB 8192
#define ND 128
#define MARGINF 0.3f
#define FLTMAX 3.402823466e+38f
#define A_TILES 8             // scan cap: 8 x 16 = 128 cols
#define FIN_BLOCKS 1024       // 8 row-groups x 128 chunks
#define DIAG_COL 0xFFFFFFFEULL

// ws layout (bytes):
//   [0]      uint  pd0               (reset by scan block 0)
//   [256]    uint  pd1[32] @64B str. (reset by scan block 0)
//   [4096]   float dapw[8192]
//   [36864]  float row_loss[8192]    (-1.0f = unresolved sentinel)
//   [69632]  int   list[8192]        (row | -1)
//   [102400] u64   idxval[8192]      (~0 for unresolved; finish atomicMins)

__device__ __forceinline__ float dot4(float4 x, float4 y) {
    return x.x * y.x + x.y * y.y + x.z * y.z + x.w * y.w;
}

// Butterfly sum within each 32-lane half.
__device__ __forceinline__ float half_reduce(float v) {
    v += __shfl_xor(v, 1, 64);
    v += __shfl_xor(v, 2, 64);
    v += __shfl_xor(v, 4, 64);
    v += __shfl_xor(v, 8, 64);
    v += __shfl_xor(v, 16, 64);
    return v;
}

// Lane owning local column c: col(L) = 2*(L&31) + (L>>5).
__device__ __forceinline__ int owner(int c) {
    return (c & 1) ? 32 + (c >> 1) : (c >> 1);
}

__device__ __forceinline__ int first_col_from_mask(unsigned long long mask) {
    const unsigned int lo = (unsigned int)mask;          // even local cols
    const unsigned int hi = (unsigned int)(mask >> 32);  // odd local cols
    const int ce = lo ? 2 * (__ffs(lo) - 1)     : 0x7fffffff;
    const int co = hi ? 2 * (__ffs(hi) - 1) + 1 : 0x7fffffff;
    return ce < co ? ce : co;
}

// Node 1: one row per wave, scan cols [0,128) in 16-col mini-tiles, early exit.
// Dense outputs -> no init node. Block 0 resets the arrival counters.
__global__ __launch_bounds__(256) void triplet_scan(const float* __restrict__ a,
                                                    const float* __restrict__ p,
                                                    const float* __restrict__ n,
                                                    unsigned int* __restrict__ hdr,
                                                    float* __restrict__ dapw,
                                                    float* __restrict__ row_loss,
                                                    int* __restrict__ list,
                                                    unsigned long long* __restrict__ idxval) {
    const int tid  = threadIdx.x;
    const int wave = tid >> 6;
    const int lane = tid & 63;
    const int q    = lane & 31;
    const int h    = lane >> 5;
    const int row  = blockIdx.x * 4 + wave;

    if (blockIdx.x == 0) {                    // reset arrival counters (boundary-ordered)
        if (tid == 0) hdr[0] = 0u;            // pd0
        if (tid < 32) hdr[64 + tid * 16] = 0u;// pd1[tid] (64B stride from ws+256)
    }

    const float4 a4 = *(const float4*)(a + (size_t)row * ND + q * 4);
    const float4 p4 = *(const float4*)(p + (size_t)row * ND + q * 4);
    const float dist_ap = half_reduce(dot4(a4, p4));
    const float thresh  = dist_ap + MARGINF;

    float loss = -1.0f;                       // unresolved sentinel
    bool resolved = false;
    for (int t = 0; t < A_TILES && !resolved; ++t) {
        float myval = FLTMAX;
        #pragma unroll
        for (int k = 0; k < 8; ++k) {
            const int col = t * 16 + 2 * k + h;
            const float4 nv = *(const float4*)(n + (size_t)col * ND + q * 4);
            const float v = half_reduce(dot4(a4, nv));
            if (q == k) myval = v;
        }
        const unsigned long long mask = __ballot(myval < thresh);
        if (mask) {  // wave-uniform: first tile with a hit; min col inside is exact
            const int c = first_col_from_mask(mask);
            const float dist_an = __shfl(myval, owner(c), 64);
            const float l = dist_an - dist_ap + MARGINF;
            loss = l > 0.f ? l : 0.f;
            resolved = true;
        }
    }
    if (lane == 0) {
        dapw[row]     = dist_ap;
        row_loss[row] = loss;
        list[row]     = resolved ? -1 : row;
        if (!resolved) idxval[row] = ~0ULL;
    }
}

// Node 2: block (rg, cg); compact rg-slice's unresolved rows in LDS, each wave
// does one (row, chunk cg) tile -> relaxed atomicMin. Hierarchical arrival
// (32 padded L1 counters -> 1 L0 counter); last block runs the finale.
__global__ __launch_bounds__(256) void triplet_finish(const float* __restrict__ a,
                                                      const float* __restrict__ n,
                                                      const float* __restrict__ dapw,
                                                      const float* __restrict__ row_loss,
                                                      const int* __restrict__ list,
                                                      unsigned long long* __restrict__ idxval,
                                                      unsigned int* __restrict__ hdr,
                                                      float* __restrict__ out) {
    __shared__ int s_rows[1024];
    __shared__ int s_cnt;
    __shared__ int s_last;
    __shared__ double s_red[256];
    const int tid  = threadIdx.x;
    const int wave = tid >> 6;
    const int lane = tid & 63;
    const int q    = lane & 31;
    const int h    = lane >> 5;
    const int cg   = blockIdx.x & 127;        // chunk index [0,128)
    const int rg   = blockIdx.x >> 7;         // row-group [0,8)
    const int tb   = cg << 6;                 // chunk base column

    if (tid == 0) s_cnt = 0;
    __syncthreads();
    #pragma unroll
    for (int i = 0; i < 4; ++i) {             // 1024 ints, coalesced
        const int v = list[rg * 1024 + i * 256 + tid];
        if (v >= 0) s_rows[atomicAdd(&s_cnt, 1)] = v;   // LDS atomic; order moot
    }
    __syncthreads();
    const int cnt = s_cnt;

    for (int t = wave; t < cnt; t += 4) {
        const int r  = s_rows[t];
        const float th = dapw[r] + MARGINF;
        const float4 a4 = *(const float4*)(a + (size_t)r * ND + q * 4);

        float myval = FLTMAX;
        #pragma unroll
        for (int k = 0; k < 32; ++k) {
            const int col = tb + 2 * k + h;
            const float4 nv = *(const float4*)(n + (size_t)col * ND + q * 4);
            const float v = half_reduce(dot4(a4, nv));   // bit-identical to scan
            if (q == k) myval = v;
        }
        if ((r >> 6) == cg) {                 // diag candidate (loses to any hit)
            const float dv = __shfl(myval, owner(r - tb), 64);
            if (lane == 0) {
                const unsigned long long dkey =
                    (DIAG_COL << 32) | (unsigned long long)__float_as_uint(dv);
                atomicMin(&idxval[r], dkey);
            }
        }
        const unsigned long long mask = __ballot(myval < th);
        if (mask) {                           // wave-uniform
            const int c = first_col_from_mask(mask);
            const float fv = __shfl(myval, owner(c), 64);
            if (lane == 0) {
                const unsigned long long key =
                    ((unsigned long long)(tb + c) << 32)
                    | (unsigned long long)__float_as_uint(fv);
                atomicMin(&idxval[r], key);   // min col wins; order-independent
            }
        }
    }

    // Hierarchical arrival: barrier drains this block's atomics first.
    __syncthreads();
    if (tid == 0) {
        s_last = 0;
        const int g = blockIdx.x >> 5;        // 32 groups of 32 blocks
        const unsigned int o1 = atomicAdd(&hdr[64 + g * 16], 1u);
        if (o1 == 31u) {                      // last block of this group
            const unsigned int o0 = atomicAdd(&hdr[0], 1u);
            if (o0 == 31u) s_last = 1;        // last group overall
        }
    }
    __syncthreads();
    if (!s_last) return;

    // Finale (last block only): fixed-order deterministic sum.
    double sum = 0.0;
    #pragma unroll
    for (int i = 0; i < NB / 256; ++i) {      // 32 iters, fixed order
        const int w = i * 256 + tid;
        float v = row_loss[w];
        if (v < 0.f) {                        // sentinel: read atomics' result
            const unsigned long long u = atomicAdd(&idxval[w], 0ULL);
            const float an_v = __uint_as_float((unsigned int)u);
            const float l = an_v - dapw[w] + MARGINF;
            v = l > 0.f ? l : 0.f;
        }
        sum += (double)v;
    }
    s_red[tid] = sum;
    __syncthreads();
    #pragma unroll
    for (int off = 128; off; off >>= 1) {
        if (tid < off) s_red[tid] += s_red[tid + off];
        __syncthreads();
    }
    if (tid == 0) out[0] = (float)(s_red[0] / (double)NB);
}

extern "C" void kernel_launch(void* const* d_in, const int* in_sizes, int n_in,
                              void* d_out, int out_size, void* d_ws, size_t ws_size,
                              hipStream_t stream) {
    const float* a = (const float*)d_in[0];
    const float* p = (const float*)d_in[1];
    const float* n = (const float*)d_in[2];
    float* out = (float*)d_out;
    char*  ws  = (char*)d_ws;
    unsigned int*       hdr      = (unsigned int*)ws;           // pd0 @0, pd1 @256+g*64
    float*              dapw     = (float*)(ws + 4096);
    float*              row_loss = (float*)(ws + 36864);
    int*                list     = (int*)(ws + 69632);
    unsigned long long* idxval   = (unsigned long long*)(ws + 102400);

    triplet_scan  <<<NB / 4, 256, 0, stream>>>(a, p, n, hdr, dapw, row_loss, list, idxval);
    triplet_finish<<<FIN_BLOCKS, 256, 0, stream>>>(a, n, dapw, row_loss, list, idxval, hdr, out);
}

// Round 15
// 60.479 us; speedup vs baseline: 1.0097x; 1.0003x over previous
//
#include <hip/hip_runtime.h>

#define NB 8192
#define ND 128
#define MARGINF 0.3f
#define FLTMAX 3.402823466e+38f
#define A_TILES 8             // scan cap: 8 x 16 = 128 cols
#define FIN_BLOCKS 1024       // 8 row-groups x 128 chunks
#define DIAG_COL 0xFFFFFFFEULL

// ws layout (bytes):
//   [0]      uint  pd             (reset by scan block 0)
//   [4096]   float dapw[8192]
//   [36864]  float row_loss[8192] (-1.0f = unresolved sentinel)
//   [69632]  int   list[8192]     (row | -1)
//   [102400] u64   idxval[8192]   (~0 for unresolved; finish atomicMins)

__device__ __forceinline__ float dot4(float4 x, float4 y) {
    return x.x * y.x + x.y * y.y + x.z * y.z + x.w * y.w;
}

// Butterfly sum within each 32-lane half.
__device__ __forceinline__ float half_reduce(float v) {
    v += __shfl_xor(v, 1, 64);
    v += __shfl_xor(v, 2, 64);
    v += __shfl_xor(v, 4, 64);
    v += __shfl_xor(v, 8, 64);
    v += __shfl_xor(v, 16, 64);
    return v;
}

// Lane owning local column c: col(L) = 2*(L&31) + (L>>5).
__device__ __forceinline__ int owner(int c) {
    return (c & 1) ? 32 + (c >> 1) : (c >> 1);
}

__device__ __forceinline__ int first_col_from_mask(unsigned long long mask) {
    const unsigned int lo = (unsigned int)mask;          // even local cols
    const unsigned int hi = (unsigned int)(mask >> 32);  // odd local cols
    const int ce = lo ? 2 * (__ffs(lo) - 1)     : 0x7fffffff;
    const int co = hi ? 2 * (__ffs(hi) - 1) + 1 : 0x7fffffff;
    return ce < co ? ce : co;
}

// Node 1: one row per wave, scan cols [0,128) in 16-col mini-tiles, early exit.
// Dense outputs -> no init node. Block 0 resets the arrival counter.
__global__ __launch_bounds__(256) void triplet_scan(const float* __restrict__ a,
                                                    const float* __restrict__ p,
                                                    const float* __restrict__ n,
                                                    unsigned int* __restrict__ pd,
                                                    float* __restrict__ dapw,
                                                    float* __restrict__ row_loss,
                                                    int* __restrict__ list,
                                                    unsigned long long* __restrict__ idxval) {
    const int tid  = threadIdx.x;
    const int wave = tid >> 6;
    const int lane = tid & 63;
    const int q    = lane & 31;
    const int h    = lane >> 5;
    const int row  = blockIdx.x * 4 + wave;

    if (blockIdx.x == 0 && tid == 0) *pd = 0u;   // boundary-ordered for node 2

    const float4 a4 = *(const float4*)(a + (size_t)row * ND + q * 4);
    const float4 p4 = *(const float4*)(p + (size_t)row * ND + q * 4);
    const float dist_ap = half_reduce(dot4(a4, p4));
    const float thresh  = dist_ap + MARGINF;

    float loss = -1.0f;                       // unresolved sentinel
    bool resolved = false;
    for (int t = 0; t < A_TILES && !resolved; ++t) {
        float myval = FLTMAX;
        #pragma unroll
        for (int k = 0; k < 8; ++k) {
            const int col = t * 16 + 2 * k + h;
            const float4 nv = *(const float4*)(n + (size_t)col * ND + q * 4);
            const float v = half_reduce(dot4(a4, nv));
            if (q == k) myval = v;
        }
        const unsigned long long mask = __ballot(myval < thresh);
        if (mask) {  // wave-uniform: first tile with a hit; min col inside is exact
            const int c = first_col_from_mask(mask);
            const float dist_an = __shfl(myval, owner(c), 64);
            const float l = dist_an - dist_ap + MARGINF;
            loss = l > 0.f ? l : 0.f;
            resolved = true;
        }
    }
    if (lane == 0) {
        dapw[row]     = dist_ap;
        row_loss[row] = loss;
        list[row]     = resolved ? -1 : row;
        if (!resolved) idxval[row] = ~0ULL;
    }
}

// Node 2: block (rg, cg); compact rg-slice's unresolved rows in LDS, each wave
// does one (row, chunk cg) tile -> relaxed atomicMin. Single arrival counter;
// last block: ONE threadfence (acquire) then PLAIN-LOAD finale.
__global__ __launch_bounds__(256) void triplet_finish(const float* __restrict__ a,
                                                      const float* __restrict__ n,
                                                      const float* __restrict__ dapw,
                                                      const float* __restrict__ row_loss,
                                                      const int* __restrict__ list,
                                                      unsigned long long* __restrict__ idxval,
                                                      unsigned int* __restrict__ pd,
                                                      float* __restrict__ out) {
    __shared__ int s_rows[1024];
    __shared__ int s_cnt;
    __shared__ int s_last;
    __shared__ double s_red[256];
    const int tid  = threadIdx.x;
    const int wave = tid >> 6;
    const int lane = tid & 63;
    const int q    = lane & 31;
    const int h    = lane >> 5;
    const int cg   = blockIdx.x & 127;        // chunk index [0,128)
    const int rg   = blockIdx.x >> 7;         // row-group [0,8)
    const int tb   = cg << 6;                 // chunk base column

    if (tid == 0) s_cnt = 0;
    __syncthreads();
    #pragma unroll
    for (int i = 0; i < 4; ++i) {             // 1024 ints, coalesced
        const int v = list[rg * 1024 + i * 256 + tid];
        if (v >= 0) s_rows[atomicAdd(&s_cnt, 1)] = v;   // LDS atomic; order moot
    }
    __syncthreads();
    const int cnt = s_cnt;

    for (int t = wave; t < cnt; t += 4) {
        const int r  = s_rows[t];
        const float th = dapw[r] + MARGINF;
        const float4 a4 = *(const float4*)(a + (size_t)r * ND + q * 4);

        float myval = FLTMAX;
        #pragma unroll
        for (int k = 0; k < 32; ++k) {
            const int col = tb + 2 * k + h;
            const float4 nv = *(const float4*)(n + (size_t)col * ND + q * 4);
            const float v = half_reduce(dot4(a4, nv));   // bit-identical to scan
            if (q == k) myval = v;
        }
        if ((r >> 6) == cg) {                 // diag candidate (loses to any hit)
            const float dv = __shfl(myval, owner(r - tb), 64);
            if (lane == 0) {
                const unsigned long long dkey =
                    (DIAG_COL << 32) | (unsigned long long)__float_as_uint(dv);
                atomicMin(&idxval[r], dkey);
            }
        }
        const unsigned long long mask = __ballot(myval < th);
        if (mask) {                           // wave-uniform
            const int c = first_col_from_mask(mask);
            const float fv = __shfl(myval, owner(c), 64);
            if (lane == 0) {
                const unsigned long long key =
                    ((unsigned long long)(tb + c) << 32)
                    | (unsigned long long)__float_as_uint(fv);
                atomicMin(&idxval[r], key);   // min col wins; order-independent
            }
        }
    }

    // Arrival: barrier drains this block's atomics (vmcnt before s_barrier).
    __syncthreads();
    if (tid == 0) {
        const unsigned int old = atomicAdd(pd, 1u);
        s_last = (old == FIN_BLOCKS - 1u) ? 1 : 0;
    }
    __syncthreads();
    if (!s_last) return;

    // Finale (last block only): one acquire fence, then PLAIN loads.
    __threadfence();                          // invalidate local caches once
    double sum = 0.0;
    #pragma unroll
    for (int i = 0; i < NB / 256; ++i) {      // 32 iters, fixed order
        const int w = i * 256 + tid;
        float v = row_loss[w];
        if (v < 0.f) {                        // sentinel: plain load of final key
            const unsigned long long u = idxval[w];
            const float an_v = __uint_as_float((unsigned int)u);
            const float l = an_v - dapw[w] + MARGINF;
            v = l > 0.f ? l : 0.f;
        }
        sum += (double)v;
    }
    s_red[tid] = sum;
    __syncthreads();
    #pragma unroll
    for (int off = 128; off; off >>= 1) {
        if (tid < off) s_red[tid] += s_red[tid + off];
        __syncthreads();
    }
    if (tid == 0) out[0] = (float)(s_red[0] / (double)NB);
}

extern "C" void kernel_launch(void* const* d_in, const int* in_sizes, int n_in,
                              void* d_out, int out_size, void* d_ws, size_t ws_size,
                              hipStream_t stream) {
    const float* a = (const float*)d_in[0];
    const float* p = (const float*)d_in[1];
    const float* n = (const float*)d_in[2];
    float* out = (float*)d_out;
    char*  ws  = (char*)d_ws;
    unsigned int*       pd       = (unsigned int*)ws;
    float*              dapw     = (float*)(ws + 4096);
    float*              row_loss = (float*)(ws + 36864);
    int*                list     = (int*)(ws + 69632);
    unsigned long long* idxval   = (unsigned long long*)(ws + 102400);

    triplet_scan  <<<NB / 4, 256, 0, stream>>>(a, p, n, pd, dapw, row_loss, list, idxval);
    triplet_finish<<<FIN_BLOCKS, 256, 0, stream>>>(a, n, dapw, row_loss, list, idxval, pd, out);
}

// Round 16
// 43.138 us; speedup vs baseline: 1.4156x; 1.4020x over previous
//
#include <hip/hip_runtime.h>

#define NB 8192
#define ND 128
#define MARGINF 0.3f
#define FLTMAX 3.402823466e+38f
#define A_TILES 8             // scan cap: 8 x 16 = 128 cols
#define FIN_BLOCKS 1024       // 8 row-groups x 128 chunks
#define DIAG_COL 0xFFFFFFFEULL
#define SCALEQ 33554432.0     // 2^25 quantizer -> integer sums, order-independent

// ws layout (bytes):
//   [0]      uint  pd              (reset by scan block 0)
//   [16]     u64   acc             (reset by scan block 0)
//   [4096]   float dapw[8192]      dense (scan)
//   [36864]  int   list[8192]      dense: row | -1 (scan)
//   [69632]  uint  rem[8192]       128 for unresolved rows (scan)
//   [102400] u64   idxval[8192]    ~0 for unresolved (scan); finish atomicMins
//   [168000] i64   part[2048]      per-scan-block quantized partials (plain)

__device__ __forceinline__ float dot4(float4 x, float4 y) {
    return x.x * y.x + x.y * y.y + x.z * y.z + x.w * y.w;
}

// Butterfly sum within each 32-lane half.
__device__ __forceinline__ float half_reduce(float v) {
    v += __shfl_xor(v, 1, 64);
    v += __shfl_xor(v, 2, 64);
    v += __shfl_xor(v, 4, 64);
    v += __shfl_xor(v, 8, 64);
    v += __shfl_xor(v, 16, 64);
    return v;
}

// Lane owning local column c: col(L) = 2*(L&31) + (L>>5).
__device__ __forceinline__ int owner(int c) {
    return (c & 1) ? 32 + (c >> 1) : (c >> 1);
}

__device__ __forceinline__ int first_col_from_mask(unsigned long long mask) {
    const unsigned int lo = (unsigned int)mask;          // even local cols
    const unsigned int hi = (unsigned int)(mask >> 32);  // odd local cols
    const int ce = lo ? 2 * (__ffs(lo) - 1)     : 0x7fffffff;
    const int co = hi ? 2 * (__ffs(hi) - 1) + 1 : 0x7fffffff;
    return ce < co ? ce : co;
}

// Node 1: one row per wave, scan cols [0,128) with early exit. Dense outputs;
// per-block resolved-loss partial -> plain store (no init, no atomics).
__global__ __launch_bounds__(256) void triplet_scan(const float* __restrict__ a,
                                                    const float* __restrict__ p,
                                                    const float* __restrict__ n,
                                                    unsigned int* __restrict__ pd,
                                                    unsigned long long* __restrict__ acc,
                                                    float* __restrict__ dapw,
                                                    int* __restrict__ list,
                                                    unsigned int* __restrict__ rem,
                                                    unsigned long long* __restrict__ idxval,
                                                    long long* __restrict__ part) {
    __shared__ float s_part[4];
    const int tid  = threadIdx.x;
    const int wave = tid >> 6;
    const int lane = tid & 63;
    const int q    = lane & 31;
    const int h    = lane >> 5;
    const int row  = blockIdx.x * 4 + wave;

    if (blockIdx.x == 0 && tid == 0) { *pd = 0u; *acc = 0ULL; }  // boundary-ordered

    const float4 a4 = *(const float4*)(a + (size_t)row * ND + q * 4);
    const float4 p4 = *(const float4*)(p + (size_t)row * ND + q * 4);
    const float dist_ap = half_reduce(dot4(a4, p4));
    const float thresh  = dist_ap + MARGINF;

    float lsum = 0.f;
    bool resolved = false;
    for (int t = 0; t < A_TILES && !resolved; ++t) {
        float myval = FLTMAX;
        #pragma unroll
        for (int k = 0; k < 8; ++k) {
            const int col = t * 16 + 2 * k + h;
            const float4 nv = *(const float4*)(n + (size_t)col * ND + q * 4);
            const float v = half_reduce(dot4(a4, nv));
            if (q == k) myval = v;
        }
        const unsigned long long mask = __ballot(myval < thresh);
        if (mask) {  // wave-uniform: first tile with a hit; min col inside is exact
            const int c = first_col_from_mask(mask);
            const float dist_an = __shfl(myval, owner(c), 64);
            const float l = dist_an - dist_ap + MARGINF;
            lsum = l > 0.f ? l : 0.f;
            resolved = true;
        }
    }
    if (lane == 0) {
        dapw[row] = dist_ap;
        list[row] = resolved ? -1 : row;
        if (!resolved) { idxval[row] = ~0ULL; rem[row] = 128u; }
        s_part[wave] = lsum;
    }
    __syncthreads();
    if (tid == 0) {
        const double bs = (double)s_part[0] + (double)s_part[1]
                        + (double)s_part[2] + (double)s_part[3];
        part[blockIdx.x] = llrint(bs * SCALEQ);   // plain store, dense
    }
}

// Node 2: fold part[] into acc; R11's balanced (row,chunk) atomicMin loop;
// per-row rem countdown finalizes each unresolved row's loss into acc
// (Min->Sub ordered by raw s_waitcnt, no cache-flushing fence).
// Arrival counter; last block writes out[0] from acc — O(1) tail.
__global__ __launch_bounds__(256) void triplet_finish(const float* __restrict__ a,
                                                      const float* __restrict__ n,
                                                      const float* __restrict__ dapw,
                                                      const int* __restrict__ list,
                                                      unsigned int* __restrict__ rem,
                                                      unsigned long long* __restrict__ idxval,
                                                      const long long* __restrict__ part,
                                                      unsigned int* __restrict__ pd,
                                                      unsigned long long* __restrict__ acc,
                                                      float* __restrict__ out) {
    __shared__ int s_rows[1024];
    __shared__ int s_cnt;
    __shared__ int s_last;
    const int tid  = threadIdx.x;
    const int wave = tid >> 6;
    const int lane = tid & 63;
    const int q    = lane & 31;
    const int h    = lane >> 5;
    const int cg   = blockIdx.x & 127;        // chunk index [0,128)
    const int rg   = blockIdx.x >> 7;         // row-group [0,8)
    const int tb   = cg << 6;                 // chunk base column

    if (tid == 0) {                           // fold 2 scan partials into acc
        s_cnt = 0;
        const long long s2 = part[2 * blockIdx.x] + part[2 * blockIdx.x + 1];
        if (s2 != 0) atomicAdd(acc, (unsigned long long)s2);
    }
    __syncthreads();
    #pragma unroll
    for (int i = 0; i < 4; ++i) {             // 1024 ints, coalesced
        const int v = list[rg * 1024 + i * 256 + tid];
        if (v >= 0) s_rows[atomicAdd(&s_cnt, 1)] = v;   // LDS atomic; order moot
    }
    __syncthreads();
    const int cnt = s_cnt;

    for (int t = wave; t < cnt; t += 4) {
        const int r  = s_rows[t];
        const float dap = dapw[r];
        const float th  = dap + MARGINF;
        const float4 a4 = *(const float4*)(a + (size_t)r * ND + q * 4);

        float myval = FLTMAX;
        #pragma unroll
        for (int k = 0; k < 32; ++k) {
            const int col = tb + 2 * k + h;
            const float4 nv = *(const float4*)(n + (size_t)col * ND + q * 4);
            const float v = half_reduce(dot4(a4, nv));   // bit-identical to scan
            if (q == k) myval = v;
        }
        if ((r >> 6) == cg) {                 // diag candidate (loses to any hit)
            const float dv = __shfl(myval, owner(r - tb), 64);
            if (lane == 0) {
                const unsigned long long dkey =
                    (DIAG_COL << 32) | (unsigned long long)__float_as_uint(dv);
                atomicMin(&idxval[r], dkey);
            }
        }
        const unsigned long long mask = __ballot(myval < th);
        if (mask) {                           // wave-uniform
            const int c = first_col_from_mask(mask);
            const float fv = __shfl(myval, owner(c), 64);
            if (lane == 0) {
                const unsigned long long key =
                    ((unsigned long long)(tb + c) << 32)
                    | (unsigned long long)__float_as_uint(fv);
                atomicMin(&idxval[r], key);   // min col wins; order-independent
            }
        }
        if (lane == 0) {
            // Order: Mins complete at coherence point before the countdown.
            asm volatile("s_waitcnt vmcnt(0)" ::: "memory");
            const unsigned int old = atomicSub(&rem[r], 1u);
            if (old == 1u) {                  // 128th chunk: finalize this row
                const unsigned long long u = atomicAdd(&idxval[r], 0ULL);
                const float an_v = __uint_as_float((unsigned int)u);  // hit or diag
                const float l = an_v - dap + MARGINF;
                if (l > 0.f)
                    atomicAdd(acc, (unsigned long long)llrint((double)l * SCALEQ));
            }
        }
    }

    // Arrival (barrier drains this block's atomics); last block: O(1) tail.
    __syncthreads();
    if (tid == 0) {
        const unsigned int old = atomicAdd(pd, 1u);
        s_last = (old == FIN_BLOCKS - 1u) ? 1 : 0;
    }
    __syncthreads();
    if (!s_last) return;
    if (tid == 0) {
        const unsigned long long s = atomicAdd(acc, 0ULL);
        out[0] = (float)((double)s / SCALEQ / (double)NB);
    }
}

extern "C" void kernel_launch(void* const* d_in, const int* in_sizes, int n_in,
                              void* d_out, int out_size, void* d_ws, size_t ws_size,
                              hipStream_t stream) {
    const float* a = (const float*)d_in[0];
    const float* p = (const float*)d_in[1];
    const float* n = (const float*)d_in[2];
    float* out = (float*)d_out;
    char*  ws  = (char*)d_ws;
    unsigned int*       pd     = (unsigned int*)ws;
    unsigned long long* acc    = (unsigned long long*)(ws + 16);
    float*              dapw   = (float*)(ws + 4096);
    int*                list   = (int*)(ws + 36864);
    unsigned int*       rem    = (unsigned int*)(ws + 69632);
    unsigned long long* idxval = (unsigned long long*)(ws + 102400);
    long long*          part   = (long long*)(ws + 168000);

    triplet_scan  <<<NB / 4, 256, 0, stream>>>(a, p, n, pd, acc, dapw, list, rem, idxval, part);
    triplet_finish<<<FIN_BLOCKS, 256, 0, stream>>>(a, n, dapw, list, rem, idxval, part, pd, acc, out);
}

// Round 17
// 41.375 us; speedup vs baseline: 1.4759x; 1.0426x over previous
//
#include <hip/hip_runtime.h>

#define NB 8192
#define ND 128
#define MARGINF 0.3f
#define FLTMAX 3.402823466e+38f
#define A_TILES 8             // scan cap: 8 x 16 = 128 cols
#define DIAG_COL 0xFFFFFFFEULL

// ws layout (bytes):
//   [0]      float dapw[8192]     dense, written every call
//   [32768]  u64   idxval[8192]   dense: resolved key or ~0; finish atomicMins
//   [98304]  int   list[8192]     row if unresolved else -1
// total 128 KB

__device__ __forceinline__ float dot4(float4 x, float4 y) {
    return x.x * y.x + x.y * y.y + x.z * y.z + x.w * y.w;
}

// Butterfly sum within each 32-lane half.
__device__ __forceinline__ float half_reduce(float v) {
    v += __shfl_xor(v, 1, 64);
    v += __shfl_xor(v, 2, 64);
    v += __shfl_xor(v, 4, 64);
    v += __shfl_xor(v, 8, 64);
    v += __shfl_xor(v, 16, 64);
    return v;
}

// Lane owning local column c: col(L) = 2*(L&31) + (L>>5).
__device__ __forceinline__ int owner(int c) {
    return (c & 1) ? 32 + (c >> 1) : (c >> 1);
}

__device__ __forceinline__ int first_col_from_mask(unsigned long long mask) {
    const unsigned int lo = (unsigned int)mask;          // even local cols
    const unsigned int hi = (unsigned int)(mask >> 32);  // odd local cols
    const int ce = lo ? 2 * (__ffs(lo) - 1)     : 0x7fffffff;
    const int co = hi ? 2 * (__ffs(hi) - 1) + 1 : 0x7fffffff;
    return ce < co ? ce : co;
}

// Node 1: one row per wave, scan cols [0,128) in 16-col mini-tiles, early exit.
// Dense outputs only -> no init node, no global atomics.
__global__ __launch_bounds__(256) void triplet_scan(const float* __restrict__ a,
                                                    const float* __restrict__ p,
                                                    const float* __restrict__ n,
                                                    float* __restrict__ dapw,
                                                    unsigned long long* __restrict__ idxval,
                                                    int* __restrict__ list) {
    const int tid  = threadIdx.x;
    const int wave = tid >> 6;
    const int lane = tid & 63;
    const int q    = lane & 31;
    const int h    = lane >> 5;
    const int row  = blockIdx.x * 4 + wave;

    const float4 a4 = *(const float4*)(a + (size_t)row * ND + q * 4);
    const float4 p4 = *(const float4*)(p + (size_t)row * ND + q * 4);
    const float dist_ap = half_reduce(dot4(a4, p4));
    const float thresh  = dist_ap + MARGINF;

    unsigned long long result = ~0ULL;        // unresolved sentinel
    for (int t = 0; t < A_TILES; ++t) {
        float myval = FLTMAX;
        #pragma unroll
        for (int k = 0; k < 8; ++k) {
            const int col = t * 16 + 2 * k + h;
            const float4 nv = *(const float4*)(n + (size_t)col * ND + q * 4);
            const float v = half_reduce(dot4(a4, nv));
            if (q == k) myval = v;
        }
        const unsigned long long mask = __ballot(myval < thresh);
        if (mask) {  // wave-uniform: first tile with a hit; min col inside is exact
            const int c = first_col_from_mask(mask);
            const float dist_an = __shfl(myval, owner(c), 64);
            result = ((unsigned long long)(t * 16 + c) << 32)
                   | (unsigned long long)__float_as_uint(dist_an);
            break;
        }
    }
    if (lane == 0) {
        dapw[row]   = dist_ap;
        idxval[row] = result;
        list[row]   = (result == ~0ULL) ? row : -1;
    }
}

// Node 2: block (rg, cg) = (blockIdx>>7, blockIdx&127). Compact the rg-slice's
// unresolved rows in LDS, then each wave computes one (row, chunk cg) tile and
// atomicMins the packed key. 128 blocks per row -> perfectly spread.
__global__ __launch_bounds__(256) void triplet_finish(const float* __restrict__ a,
                                                      const float* __restrict__ n,
                                                      const float* __restrict__ dapw,
                                                      const int* __restrict__ list,
                                                      unsigned long long* __restrict__ idxval) {
    __shared__ int s_rows[1024];
    __shared__ int s_cnt;
    const int tid  = threadIdx.x;
    const int wave = tid >> 6;
    const int lane = tid & 63;
    const int q    = lane & 31;
    const int h    = lane >> 5;
    const int cg   = blockIdx.x & 127;        // chunk index [0,128)
    const int rg   = blockIdx.x >> 7;         // row-group [0,8)
    const int tb   = cg << 6;                 // chunk base column

    if (tid == 0) s_cnt = 0;
    __syncthreads();
    #pragma unroll
    for (int i = 0; i < 4; ++i) {             // 1024 ints, coalesced
        const int v = list[rg * 1024 + i * 256 + tid];
        if (v >= 0) s_rows[atomicAdd(&s_cnt, 1)] = v;   // LDS atomic; order moot
    }
    __syncthreads();
    const int cnt = s_cnt;

    for (int t = wave; t < cnt; t += 4) {
        const int r  = s_rows[t];
        const float th = dapw[r] + MARGINF;
        const float4 a4 = *(const float4*)(a + (size_t)r * ND + q * 4);

        float myval = FLTMAX;
        #pragma unroll
        for (int k = 0; k < 32; ++k) {
            const int col = tb + 2 * k + h;
            const float4 nv = *(const float4*)(n + (size_t)col * ND + q * 4);
            const float v = half_reduce(dot4(a4, nv));   // bit-identical to scan
            if (q == k) myval = v;
        }
        if ((r >> 6) == cg) {                 // diag candidate (loses to any hit)
            const float dv = __shfl(myval, owner(r - tb), 64);
            if (lane == 0) {
                const unsigned long long dkey =
                    (DIAG_COL << 32) | (unsigned long long)__float_as_uint(dv);
                atomicMin(&idxval[r], dkey);
            }
        }
        const unsigned long long mask = __ballot(myval < th);
        if (mask) {                           // wave-uniform
            const int c = first_col_from_mask(mask);
            const float fv = __shfl(myval, owner(c), 64);
            if (lane == 0) {
                const unsigned long long key =
                    ((unsigned long long)(tb + c) << 32)
                    | (unsigned long long)__float_as_uint(fv);
                atomicMin(&idxval[r], key);   // min col wins; order-independent
            }
        }
    }
}

// Node 3: 1 block, fixed-order deterministic sum of all 8192 losses.
__global__ __launch_bounds__(256) void finale(const float* __restrict__ dapw,
                                              const unsigned long long* __restrict__ idxval,
                                              float* __restrict__ out) {
    __shared__ double s[256];
    const int tid = threadIdx.x;
    double sum = 0.0;
    #pragma unroll
    for (int i = 0; i < NB / 256; ++i) {      // 32 iters, fixed order
        const int w = i * 256 + tid;
        const float an_v = __uint_as_float((unsigned int)idxval[w]);
        const float l = an_v - dapw[w] + MARGINF;
        if (l > 0.f) sum += (double)l;
    }
    s[tid] = sum;
    __syncthreads();
    #pragma unroll
    for (int off = 128; off; off >>= 1) {
        if (tid < off) s[tid] += s[tid + off];
        __syncthreads();
    }
    if (tid == 0) out[0] = (float)(s[0] / (double)NB);
}

extern "C" void kernel_launch(void* const* d_in, const int* in_sizes, int n_in,
                              void* d_out, int out_size, void* d_ws, size_t ws_size,
                              hipStream_t stream) {
    const float* a = (const float*)d_in[0];
    const float* p = (const float*)d_in[1];
    const float* n = (const float*)d_in[2];
    float* out = (float*)d_out;
    char*  ws  = (char*)d_ws;
    float*              dapw   = (float*)ws;
    unsigned long long* idxval = (unsigned long long*)(ws + 32768);
    int*                list   = (int*)(ws + 98304);

    triplet_scan  <<<NB / 4, 256, 0, stream>>>(a, p, n, dapw, idxval, list);
    triplet_finish<<<1024, 256, 0, stream>>>(a, n, dapw, list, idxval);
    finale        <<<1, 256, 0, stream>>>(dapw, idxval, out);
}